// Round 7
// baseline (285.440 us; speedup 1.0000x reference)
//
#include <hip/hip_runtime.h>
#include <hip/hip_bf16.h>

// Problem dims
#define NTOK 8192       // B*T
#define NASN 16384      // NTOK * K(=2)
#define C_ 512
#define H_ 2048
#define E_ 8
#define NCH 128         // token chunks for atomic spreading
#define CHTOK 64        // tokens per chunk

typedef __bf16 bf16x8 __attribute__((ext_vector_type(8)));
typedef float f32x4 __attribute__((ext_vector_type(4)));

// Workspace layout (bytes). Total ~109.4 MB.
#define WS_COUNTS 0                              // NCH*8*4 = 4096
#define WS_BASE   4096                           // NCH*8*4 = 4096
#define WS_OFFS   8192                           // 9*4 -> pad 256
#define WS_T1S    8448                           // 9*4 -> pad 256 (128-row tiles)
#define WS_T2S    8704                           // 9*4 -> pad 256 (64-row tiles)
#define WS_INFO   8960                           // NTOK*16
#define WS_TOKL   (WS_INFO + NTOK*16)            // NASN*4
#define WS_SLOTS  (WS_TOKL + NASN*4)             // NTOK*8 (int2)
#define WS_XBF    (WS_SLOTS + NTOK*8)            // NTOK*C_*2 bf16 token-ordered x
#define WS_W1B    (WS_XBF + (size_t)NTOK*C_*2)   // E*H*C bf16, [e][h][c]
#define WS_W2B    (WS_W1B + (size_t)E_*H_*C_*2)  // E*C*H bf16, [e][c][h]
#define WS_HS     (WS_W2B + (size_t)E_*H_*C_*2)  // NASN*H bf16 hidden acts
// Ys (bf16, NASN*C_*2 = 16.78 MB) aliases Xbf+W1b (25.2 MB, dead by k_gemm2).
#define WS_YS     WS_XBF

__device__ __forceinline__ unsigned int f2bf(float f) {
  __hip_bfloat16 h = __float2bfloat16(f);
  return (unsigned int)*(unsigned short*)&h;
}
__device__ __forceinline__ float bf2f(unsigned int u) {
  return __int_as_float((u & 0xffffu) << 16);
}

// async global->LDS, 16B per lane; LDS dest = wave-uniform base + lane*16
__device__ __forceinline__ void g2l16(const unsigned short* g, unsigned short* l) {
  __builtin_amdgcn_global_load_lds(
      (const __attribute__((address_space(1))) unsigned int*)g,
      (__attribute__((address_space(3))) unsigned int*)l, 16, 0, 0);
}

// Pair-interleaved XOR LDS layout for a [rows x 32 ushort] panel:
// 16B chunk of (row r, k-chunk q) lives at linear chunk (r>>1)*8 + slot,
// slot = ((r&1)*4 + q) ^ ((r>>1)&7).  Full 32-bank coverage on fragment
// reads (2 lanes/bank = free).  Staging decode for linear chunk L:
__device__ __forceinline__ void stage_decode(int L, int& brow, int& q) {
  int s = L >> 3, slot = L & 7;
  int v = slot ^ (s & 7);
  brow = 2*s + (v >> 2);
  q = v & 3;
}

// ---------------- router: one wave per token, fp32; also emits bf16 Xbf ----------------
__global__ __launch_bounds__(256) void k_router(
    const float* __restrict__ x, const float* __restrict__ Wr,
    const float* __restrict__ br, float* __restrict__ out_logits,
    float* __restrict__ out_idx, int4* __restrict__ info,
    int* __restrict__ counts, unsigned short* __restrict__ Xbf)
{
  int t = blockIdx.x * 4 + (threadIdx.x >> 6);
  int lane = threadIdx.x & 63;
  const float4* xr = (const float4*)(x + (size_t)t * C_);
  float4 x0 = xr[lane*2], x1 = xr[lane*2+1];
  uint4 pk;
  pk.x = f2bf(x0.x) | (f2bf(x0.y) << 16);
  pk.y = f2bf(x0.z) | (f2bf(x0.w) << 16);
  pk.z = f2bf(x1.x) | (f2bf(x1.y) << 16);
  pk.w = f2bf(x1.z) | (f2bf(x1.w) << 16);
  *(uint4*)(Xbf + (size_t)t * C_ + lane*8) = pk;

  float xs[8] = {x0.x,x0.y,x0.z,x0.w,x1.x,x1.y,x1.z,x1.w};
  float acc[8] = {0,0,0,0,0,0,0,0};
  #pragma unroll
  for (int j = 0; j < 8; j++) {
    const float4* w = (const float4*)(Wr + (size_t)(lane*8+j) * E_);
    float4 w0 = w[0], w1 = w[1];
    float we[8] = {w0.x,w0.y,w0.z,w0.w,w1.x,w1.y,w1.z,w1.w};
    #pragma unroll
    for (int e = 0; e < 8; e++) acc[e] += xs[j] * we[e];
  }
  #pragma unroll
  for (int off = 1; off < 64; off <<= 1) {
    #pragma unroll
    for (int e = 0; e < 8; e++) acc[e] += __shfl_xor(acc[e], off, 64);
  }
  #pragma unroll
  for (int e = 0; e < 8; e++) acc[e] += br[e];
  if (lane == 0) {
    #pragma unroll
    for (int e = 0; e < 8; e++) out_logits[t*8 + e] = acc[e];
    int i0 = 0; float v0 = acc[0];
    #pragma unroll
    for (int e = 1; e < 8; e++) if (acc[e] > v0) { v0 = acc[e]; i0 = e; }
    int i1 = -1; float v1 = -1e30f;
    #pragma unroll
    for (int e = 0; e < 8; e++) if (e != i0 && acc[e] > v1) { v1 = acc[e]; i1 = e; }
    float d = expf(v1 - v0);
    float s1 = d / (1.0f + d);
    float s0 = 1.0f - s1;
    out_idx[t*2]     = (float)i0;
    out_idx[t*2 + 1] = (float)i1;
    info[t] = make_int4(i0, i1, __float_as_int(s0), __float_as_int(s1));
    int ch = t >> 6;
    atomicAdd(&counts[ch*8 + i0], 1);
    atomicAdd(&counts[ch*8 + i1], 1);
  }
}

// ---------------- prefix: per-chunk/per-expert slot bases + tile tables ----------------
__global__ __launch_bounds__(256) void k_prefix(
    const int* __restrict__ counts, int* __restrict__ base,
    int* __restrict__ offs, int* __restrict__ t1s, int* __restrict__ t2s)
{
  __shared__ int lc[NCH*8];
  __shared__ int tot[8];
  __shared__ int off_s[9];
  int tid = threadIdx.x;
  for (int i = tid; i < NCH*8; i += 256) lc[i] = counts[i];
  __syncthreads();
  if (tid < 8) {
    int run = 0;
    for (int c = 0; c < NCH; c++) { int v = lc[c*8+tid]; lc[c*8+tid] = run; run += v; }
    tot[tid] = run;
  }
  __syncthreads();
  if (tid == 0) {
    int o = 0, t1 = 0, t2 = 0;
    off_s[0] = 0; offs[0] = 0; t1s[0] = 0; t2s[0] = 0;
    for (int e = 0; e < 8; e++) {
      o += tot[e];
      off_s[e+1] = o; offs[e+1] = o;
      t1 += (tot[e] + 127) >> 7;
      t1s[e+1] = t1;
      t2 += (tot[e] + 63) >> 6;
      t2s[e+1] = t2;
    }
  }
  __syncthreads();
  for (int i = tid; i < NCH*8; i += 256) base[i] = off_s[i & 7] + lc[i];
}

// ---------------- scatter: chunk-local LDS rank -> slots ----------------
__global__ __launch_bounds__(64) void k_scatter(
    const int4* __restrict__ info, const int* __restrict__ base,
    int* __restrict__ tokl, int2* __restrict__ slots2)
{
  __shared__ int cur[8];
  int c = blockIdx.x, tid = threadIdx.x;
  if (tid < 8) cur[tid] = base[c*8 + tid];
  __syncthreads();
  int t = c * CHTOK + tid;
  int4 nfo = info[t];
  int r0 = atomicAdd(&cur[nfo.x], 1);
  int r1 = atomicAdd(&cur[nfo.y], 1);
  tokl[r0] = t;
  tokl[r1] = t;
  slots2[t] = make_int2(r0, r1);
}

// ---------------- weight transpose fp32[R][S] -> bf16[S][R] ----------------
__global__ __launch_bounds__(256) void k_transpose(
    const float* __restrict__ in, unsigned short* __restrict__ outp, int R, int S)
{
  __shared__ float tile[128][33];
  size_t zo = (size_t)blockIdx.z * R * S;
  in += zo; outp += zo;
  int r0 = blockIdx.y * 128, s0 = blockIdx.x * 32;
  int t = threadIdx.x;
  #pragma unroll
  for (int i = 0; i < 16; i++) {
    int lin = i*256 + t;
    int rr = lin >> 5, ss = lin & 31;
    tile[rr][ss] = in[(size_t)(r0 + rr) * S + s0 + ss];
  }
  __syncthreads();
  #pragma unroll
  for (int i = 0; i < 4; i++) {
    int lin = i*256 + t;
    int ss = lin >> 5, rq = lin & 31;
    ushort4 v;
    v.x = (unsigned short)f2bf(tile[rq*4+0][ss]);
    v.y = (unsigned short)f2bf(tile[rq*4+1][ss]);
    v.z = (unsigned short)f2bf(tile[rq*4+2][ss]);
    v.w = (unsigned short)f2bf(tile[rq*4+3][ss]);
    *(ushort4*)(outp + (size_t)(s0 + ss) * R + r0 + rq*4) = v;
  }
}

// ---------------- grouped GEMM layer 1: Hs = relu(Xrows @ W1 + b1) ----------------
// 128x128 tile, BK=32, 32KB dbuf + vmcnt(4) pipeline, pair-interleaved XOR LDS.
__global__ __launch_bounds__(256) void k_gemm1(
    const unsigned short* __restrict__ Xbf, const int* __restrict__ tokl,
    const unsigned short* __restrict__ W1b,
    const float* __restrict__ b1, unsigned short* __restrict__ Hs,
    const int* __restrict__ offs, const int* __restrict__ t1s)
{
  __shared__ __align__(16) unsigned short AB[2*8192];   // 32 KB
  int b = blockIdx.x;
  int mo = b >> 7, rr = b & 127;
  int n0 = (rr >> 3) * 128;
  int mt = mo*8 + (rr & 7);
  if (mt >= t1s[8]) return;
  int e = 0;
  #pragma unroll
  for (int i = 0; i < 7; i++) if (mt >= t1s[e+1]) e++;
  int row0 = offs[e] + (mt - t1s[e]) * 128;
  int rowEnd = offs[e+1];
  int tid = threadIdx.x, lane = tid & 63, w = tid >> 6;
  int wm = (w & 1) * 64, wn = (w >> 1) * 64;
  int quad = lane >> 4, l16 = lane & 15;
  const f32x4 zero = {0.f, 0.f, 0.f, 0.f};
  f32x4 acc[4][4];
  #pragma unroll
  for (int i = 0; i < 4; i++)
    #pragma unroll
    for (int j = 0; j < 4; j++) acc[i][j] = zero;
  const unsigned short* Bsrc = W1b + ((size_t)e * H_ + n0) * C_;

  const unsigned short* ga[2]; const unsigned short* gb[2];
  int lao[2], lbo[2];
  #pragma unroll
  for (int j = 0; j < 2; j++) {
    int L = (w*2 + j)*64 + lane;
    int brow, q; stage_decode(L, brow, q);
    int gr = row0 + brow; gr = gr < NASN-1 ? gr : NASN-1;
    int trow = tokl[gr];
    ga[j] = Xbf + (size_t)trow * C_ + q*8;
    gb[j] = Bsrc + (size_t)brow * C_ + q*8;
    lao[j] = (w*2 + j)*512;
    lbo[j] = 4096 + (w*2 + j)*512;
  }
  // per-lane fragment base (pair-interleaved XOR)
  int rbase = (l16>>1)*64 + ((((l16&1)<<2) + quad) ^ (l16>>1))*8;
  const int KI = C_ / 32;   // 16

  #pragma unroll
  for (int j = 0; j < 2; j++) { g2l16(ga[j], AB + lao[j]); g2l16(gb[j], AB + lbo[j]); }

  for (int ki = 0; ki < KI; ki++) {
    int p = ki & 1;
    if (ki + 1 < KI) {
      int off = (ki + 1) * 32;
      unsigned short* nb = AB + (p ^ 1) * 8192;
      #pragma unroll
      for (int j = 0; j < 2; j++) {
        g2l16(ga[j] + off, nb + lao[j]);
        g2l16(gb[j] + off, nb + lbo[j]);
      }
      asm volatile("s_waitcnt vmcnt(4)" ::: "memory");
    } else {
      asm volatile("s_waitcnt vmcnt(0)" ::: "memory");
    }
    asm volatile("s_barrier" ::: "memory");

    const unsigned short* Ap = AB + p*8192;
    const unsigned short* Bp = Ap + 4096;
    bf16x8 af[4], bfr[4];
    #pragma unroll
    for (int i = 0; i < 4; i++)
      af[i] = *(const bf16x8*)&Ap[wm*32 + i*512 + rbase];
    #pragma unroll
    for (int j = 0; j < 4; j++)
      bfr[j] = *(const bf16x8*)&Bp[wn*32 + j*512 + rbase];
    #pragma unroll
    for (int i = 0; i < 4; i++)
      #pragma unroll
      for (int j = 0; j < 4; j++)
        acc[i][j] = __builtin_amdgcn_mfma_f32_16x16x32_bf16(af[i], bfr[j], acc[i][j], 0, 0, 0);

    asm volatile("s_waitcnt lgkmcnt(0)" ::: "memory");
    asm volatile("s_barrier" ::: "memory");
  }

  // epilogue: per-wave LDS transpose -> coalesced 16B stores
  unsigned short* Lt = AB + w*4096;   // 64x64 bf16 per wave (8 KB)
  #pragma unroll
  for (int j = 0; j < 4; j++) {
    int n = n0 + wn + j*16 + l16;
    float bias = b1[e * H_ + n];
    #pragma unroll
    for (int i = 0; i < 4; i++)
      #pragma unroll
      for (int r = 0; r < 4; r++) {
        float v = acc[i][j][r] + bias;
        Lt[(i*16 + quad*4 + r)*64 + j*16 + l16] = (unsigned short)f2bf(v > 0.f ? v : 0.f);
      }
  }
  #pragma unroll
  for (int it = 0; it < 8; it++) {
    int rloc = it*8 + (lane >> 3);
    int m = row0 + wm + rloc;
    uint4 vv = *(uint4*)&Lt[rloc*64 + (lane & 7)*8];
    if (m < rowEnd)
      *(uint4*)(Hs + (size_t)m * H_ + n0 + wn + (lane & 7)*8) = vv;
  }
}

// ---------------- grouped GEMM layer 2: Ys(bf16) = Hs @ W2 + b2 ----------------
// 64x128 tile (4 waves of 32x64), BK=32, 24KB dbuf, vmcnt(3) pipeline,
// pair-interleaved XOR LDS. Grid ~1056 blocks (4.1/CU). 1D grid, XCD swizzle.
__global__ __launch_bounds__(256) void k_gemm2(
    const unsigned short* __restrict__ Hs, const unsigned short* __restrict__ W2b,
    const float* __restrict__ b2, unsigned short* __restrict__ Ys,
    const int* __restrict__ offs, const int* __restrict__ t2s)
{
  __shared__ __align__(16) unsigned short AB[2*6144];   // 24 KB: 2 x (A 4KB + B 8KB)
  int b = blockIdx.x;
  int mo = b >> 5, rr = b & 31;
  int n0 = (rr >> 3) * 128;
  int mt = mo*8 + (rr & 7);
  if (mt >= t2s[8]) return;
  int e = 0;
  #pragma unroll
  for (int i = 0; i < 7; i++) if (mt >= t2s[e+1]) e++;
  int row0 = offs[e] + (mt - t2s[e]) * 64;
  int rowEnd = offs[e+1];
  int tid = threadIdx.x, lane = tid & 63, w = tid >> 6;
  int wm = (w & 1) * 32, wn = (w >> 1) * 64;
  int quad = lane >> 4, l16 = lane & 15;
  const f32x4 zero = {0.f, 0.f, 0.f, 0.f};
  f32x4 acc[2][4];
  #pragma unroll
  for (int i = 0; i < 2; i++)
    #pragma unroll
    for (int j = 0; j < 4; j++) acc[i][j] = zero;
  const unsigned short* Bsrc = W2b + ((size_t)e * C_ + n0) * H_;

  // staging: A panel 64x32 (4 instr, one per wave), B panel 128x32 (8 instr, 2/wave)
  const unsigned short* gA; int laoA;
  const unsigned short* gb[2]; int lbo[2];
  {
    int L = w*64 + lane;
    int brow, q; stage_decode(L, brow, q);
    int gr = row0 + brow; gr = gr < NASN-1 ? gr : NASN-1;
    gA = Hs + (size_t)gr * H_ + q*8;
    laoA = w*512;
  }
  #pragma unroll
  for (int j = 0; j < 2; j++) {
    int L = (w*2 + j)*64 + lane;
    int brow, q; stage_decode(L, brow, q);
    gb[j] = Bsrc + (size_t)brow * H_ + q*8;
    lbo[j] = 2048 + (w*2 + j)*512;
  }
  int rbase = (l16>>1)*64 + ((((l16&1)<<2) + quad) ^ (l16>>1))*8;
  const int KI = H_ / 32;   // 64

  g2l16(gA, AB + laoA);
  #pragma unroll
  for (int j = 0; j < 2; j++) g2l16(gb[j], AB + lbo[j]);

  for (int ki = 0; ki < KI; ki++) {
    int p = ki & 1;
    if (ki + 1 < KI) {
      int off = (ki + 1) * 32;
      unsigned short* nb = AB + (p ^ 1) * 6144;
      g2l16(gA + off, nb + laoA);
      #pragma unroll
      for (int j = 0; j < 2; j++) g2l16(gb[j] + off, nb + lbo[j]);
      asm volatile("s_waitcnt vmcnt(3)" ::: "memory");
    } else {
      asm volatile("s_waitcnt vmcnt(0)" ::: "memory");
    }
    asm volatile("s_barrier" ::: "memory");

    const unsigned short* Ap = AB + p*6144;
    const unsigned short* Bp = Ap + 2048;
    bf16x8 af[2], bfr[4];
    #pragma unroll
    for (int i = 0; i < 2; i++)
      af[i] = *(const bf16x8*)&Ap[wm*32 + i*512 + rbase];
    #pragma unroll
    for (int j = 0; j < 4; j++)
      bfr[j] = *(const bf16x8*)&Bp[wn*32 + j*512 + rbase];
    #pragma unroll
    for (int i = 0; i < 2; i++)
      #pragma unroll
      for (int j = 0; j < 4; j++)
        acc[i][j] = __builtin_amdgcn_mfma_f32_16x16x32_bf16(af[i], bfr[j], acc[i][j], 0, 0, 0);

    asm volatile("s_waitcnt lgkmcnt(0)" ::: "memory");
    asm volatile("s_barrier" ::: "memory");
  }

  // epilogue: per-wave 32x64 LDS transpose -> coalesced bf16 16B stores
  unsigned short* Lt = AB + w*2048;   // 4 KB per wave
  #pragma unroll
  for (int j = 0; j < 4; j++) {
    int n = n0 + wn + j*16 + l16;
    float bias = b2[e * C_ + n];
    #pragma unroll
    for (int i = 0; i < 2; i++)
      #pragma unroll
      for (int r = 0; r < 4; r++)
        Lt[(i*16 + quad*4 + r)*64 + j*16 + l16] =
            (unsigned short)f2bf(acc[i][j][r] + bias);
  }
  #pragma unroll
  for (int it = 0; it < 4; it++) {
    int rloc = it*8 + (lane >> 3);
    int m = row0 + wm + rloc;
    uint4 vv = *(uint4*)&Lt[rloc*64 + (lane & 7)*8];
    if (m < rowEnd)
      *(uint4*)(Ys + (size_t)m * C_ + n0 + wn + (lane & 7)*8) = vv;
  }
}

// ---------------- combine: out[t] = g0*Ys[s0] + g1*Ys[s1] (bf16 Ys) ----------------
__global__ __launch_bounds__(256) void k_combine(
    const unsigned short* __restrict__ Ys, const int4* __restrict__ info,
    const int2* __restrict__ slots2, float* __restrict__ outp)
{
  int t = blockIdx.x * 4 + (threadIdx.x >> 6);
  int lane = threadIdx.x & 63;
  int4 nfo = info[t];
  int2 ss = slots2[t];
  float g0 = __int_as_float(nfo.z), g1 = __int_as_float(nfo.w);
  uint4 a = *(const uint4*)(Ys + (size_t)ss.x * C_ + lane*8);
  uint4 bb = *(const uint4*)(Ys + (size_t)ss.y * C_ + lane*8);
  unsigned int au[4] = {a.x, a.y, a.z, a.w};
  unsigned int bu[4] = {bb.x, bb.y, bb.z, bb.w};
  float vals[8];
  #pragma unroll
  for (int q = 0; q < 4; q++) {
    vals[q*2]   = g0*bf2f(au[q])       + g1*bf2f(bu[q]);
    vals[q*2+1] = g0*bf2f(au[q] >> 16) + g1*bf2f(bu[q] >> 16);
  }
  float4 o0, o1;
  o0.x = vals[0]; o0.y = vals[1]; o0.z = vals[2]; o0.w = vals[3];
  o1.x = vals[4]; o1.y = vals[5]; o1.z = vals[6]; o1.w = vals[7];
  float4* o = (float4*)(outp + (size_t)t * C_ + lane*8);
  o[0] = o0;
  o[1] = o1;
}

extern "C" void kernel_launch(void* const* d_in, const int* in_sizes, int n_in,
                              void* d_out, int out_size, void* d_ws, size_t ws_size,
                              hipStream_t stream)
{
  const float* x  = (const float*)d_in[0];
  const float* Wr = (const float*)d_in[1];
  const float* br = (const float*)d_in[2];
  const float* W1 = (const float*)d_in[3];
  const float* b1 = (const float*)d_in[4];
  const float* W2 = (const float*)d_in[5];
  const float* b2 = (const float*)d_in[6];
  float* out = (float*)d_out;   // [logits 65536 | idx 16384 | out 4194304]
  char* ws = (char*)d_ws;

  int*  counts = (int*)(ws + WS_COUNTS);
  int*  base   = (int*)(ws + WS_BASE);
  int*  offs   = (int*)(ws + WS_OFFS);
  int*  t1s    = (int*)(ws + WS_T1S);
  int*  t2s    = (int*)(ws + WS_T2S);
  int4* info   = (int4*)(ws + WS_INFO);
  int*  tokl   = (int*)(ws + WS_TOKL);
  int2* slots2 = (int2*)(ws + WS_SLOTS);
  unsigned short* Xbf = (unsigned short*)(ws + WS_XBF);
  unsigned short* W1b = (unsigned short*)(ws + WS_W1B);
  unsigned short* W2b = (unsigned short*)(ws + WS_W2B);
  unsigned short* Hs  = (unsigned short*)(ws + WS_HS);
  unsigned short* Ys  = (unsigned short*)(ws + WS_YS);  // aliases Xbf+W1b

  hipMemsetAsync(counts, 0, NCH*8*sizeof(int), stream);

  k_transpose<<<dim3(H_/32, C_/128, E_), 256, 0, stream>>>(W1, W1b, C_, H_);
  k_transpose<<<dim3(C_/32, H_/128, E_), 256, 0, stream>>>(W2, W2b, H_, C_);
  k_router<<<NTOK/4, 256, 0, stream>>>(x, Wr, br, out, out + 65536, info, counts, Xbf);
  k_prefix<<<1, 256, 0, stream>>>(counts, base, offs, t1s, t2s);
  k_scatter<<<NCH, 64, 0, stream>>>(info, base, tokl, slots2);
  k_gemm1<<<17*128, 256, 0, stream>>>(Xbf, tokl, W1b, b1, Hs, offs, t1s);
  k_gemm2<<<33*32, 256, 0, stream>>>(Hs, W2b, b2, Ys, offs, t2s);
  k_combine<<<NTOK/4, 256, 0, stream>>>(Ys, info, slots2, out + 81920);
}

// Round 8
// 272.490 us; speedup vs baseline: 1.0475x; 1.0475x over previous
//
#include <hip/hip_runtime.h>
#include <hip/hip_bf16.h>

// Problem dims
#define NTOK 8192       // B*T
#define NASN 16384      // NTOK * K(=2)
#define C_ 512
#define H_ 2048
#define E_ 8
#define RBC 2048        // router blocks (4 tokens each) = count granularity

typedef __bf16 bf16x8 __attribute__((ext_vector_type(8)));
typedef float f32x4 __attribute__((ext_vector_type(4)));

// Workspace layout (bytes). Total ~109.5 MB.
#define WS_COUNTS 0                              // RBC*8*4 = 64 KB (written, not atomically)
#define WS_OFFS   65536                          // 9*4 -> pad 256
#define WS_T1S    65792                          // 9*4 -> pad 256
#define WS_INFO   66048                          // NTOK*16
#define WS_TOKL   (WS_INFO + NTOK*16)            // NASN*4
#define WS_SLOTS  (WS_TOKL + NASN*4)             // NTOK*8 (int2)
#define WS_XBF    (WS_SLOTS + NTOK*8)            // NTOK*C_*2 bf16 token-ordered x
#define WS_W1B    (WS_XBF + (size_t)NTOK*C_*2)   // E*H*C bf16, [e][h][c]
#define WS_W2B    (WS_W1B + (size_t)E_*H_*C_*2)  // E*C*H bf16, [e][c][h]
#define WS_HS     (WS_W2B + (size_t)E_*H_*C_*2)  // NASN*H bf16 hidden acts
// Ys (bf16, NASN*C_*2 = 16.78 MB) aliases Xbf+W1b (25.2 MB, dead by k_gemm2).
#define WS_YS     WS_XBF

__device__ __forceinline__ unsigned int f2bf(float f) {
  __hip_bfloat16 h = __float2bfloat16(f);
  return (unsigned int)*(unsigned short*)&h;
}
__device__ __forceinline__ float bf2f(unsigned int u) {
  return __int_as_float((u & 0xffffu) << 16);
}

// async global->LDS, 16B per lane; LDS dest = wave-uniform base + lane*16
__device__ __forceinline__ void g2l16(const unsigned short* g, unsigned short* l) {
  __builtin_amdgcn_global_load_lds(
      (const __attribute__((address_space(1))) unsigned int*)g,
      (__attribute__((address_space(3))) unsigned int*)l, 16, 0, 0);
}

// Pair-interleaved XOR LDS layout for a [rows x 32 ushort] panel:
// 16B chunk of (row r, k-chunk q) at linear chunk (r>>1)*8 + slot,
// slot = ((r&1)*4 + q) ^ ((r>>1)&7).  Full 32-bank coverage on fragment reads.
__device__ __forceinline__ void stage_decode(int L, int& brow, int& q) {
  int s = L >> 3, slot = L & 7;
  int v = slot ^ (s & 7);
  brow = 2*s + (v >> 2);
  q = v & 3;
}

// ---------------- fused: router (b<2048) | W1 transpose | W2 transpose ----------------
__global__ __launch_bounds__(256) void k_fused(
    const float* __restrict__ x, const float* __restrict__ Wr,
    const float* __restrict__ br, float* __restrict__ out_logits,
    float* __restrict__ out_idx, int4* __restrict__ info,
    int* __restrict__ counts, unsigned short* __restrict__ Xbf,
    const float* __restrict__ W1, unsigned short* __restrict__ W1b,
    const float* __restrict__ W2, unsigned short* __restrict__ W2b)
{
  __shared__ float tileS[128][33];
  __shared__ int bc[8];
  int b = blockIdx.x;
  int tid = threadIdx.x;

  if (b < RBC) {
    // ---- router: 4 tokens per block, one wave each; non-atomic counts ----
    if (tid < 8) bc[tid] = 0;
    __syncthreads();
    int t = b * 4 + (tid >> 6);
    int lane = tid & 63;
    const float4* xr = (const float4*)(x + (size_t)t * C_);
    float4 x0 = xr[lane*2], x1 = xr[lane*2+1];
    uint4 pk;
    pk.x = f2bf(x0.x) | (f2bf(x0.y) << 16);
    pk.y = f2bf(x0.z) | (f2bf(x0.w) << 16);
    pk.z = f2bf(x1.x) | (f2bf(x1.y) << 16);
    pk.w = f2bf(x1.z) | (f2bf(x1.w) << 16);
    *(uint4*)(Xbf + (size_t)t * C_ + lane*8) = pk;

    float xs[8] = {x0.x,x0.y,x0.z,x0.w,x1.x,x1.y,x1.z,x1.w};
    float acc[8] = {0,0,0,0,0,0,0,0};
    #pragma unroll
    for (int j = 0; j < 8; j++) {
      const float4* w = (const float4*)(Wr + (size_t)(lane*8+j) * E_);
      float4 w0 = w[0], w1 = w[1];
      float we[8] = {w0.x,w0.y,w0.z,w0.w,w1.x,w1.y,w1.z,w1.w};
      #pragma unroll
      for (int e = 0; e < 8; e++) acc[e] += xs[j] * we[e];
    }
    #pragma unroll
    for (int off = 1; off < 64; off <<= 1) {
      #pragma unroll
      for (int e = 0; e < 8; e++) acc[e] += __shfl_xor(acc[e], off, 64);
    }
    #pragma unroll
    for (int e = 0; e < 8; e++) acc[e] += br[e];
    if (lane == 0) {
      #pragma unroll
      for (int e = 0; e < 8; e++) out_logits[t*8 + e] = acc[e];
      int i0 = 0; float v0 = acc[0];
      #pragma unroll
      for (int e = 1; e < 8; e++) if (acc[e] > v0) { v0 = acc[e]; i0 = e; }
      int i1 = -1; float v1 = -1e30f;
      #pragma unroll
      for (int e = 0; e < 8; e++) if (e != i0 && acc[e] > v1) { v1 = acc[e]; i1 = e; }
      float d = expf(v1 - v0);
      float s1 = d / (1.0f + d);
      float s0 = 1.0f - s1;
      out_idx[t*2]     = (float)i0;
      out_idx[t*2 + 1] = (float)i1;
      info[t] = make_int4(i0, i1, __float_as_int(s0), __float_as_int(s1));
      atomicAdd(&bc[i0], 1);     // LDS atomic, block-local
      atomicAdd(&bc[i1], 1);
    }
    __syncthreads();
    if (tid < 8) counts[b*8 + tid] = bc[tid];   // full write: no memset needed
    return;
  }

  // ---- weight transposes: fp32[R][S] -> bf16[S][R] ----
  const float* in; unsigned short* outp; int R, S, bx, by, bz;
  if (b < 2*RBC) {
    int bb = b - RBC;                    // W1: R=C(512), S=H(2048)
    in = W1; outp = W1b; R = C_; S = H_;
    bx = bb & 63; by = (bb >> 6) & 3; bz = bb >> 8;
  } else {
    int bb = b - 2*RBC;                  // W2: R=H(2048), S=C(512)
    in = W2; outp = W2b; R = H_; S = C_;
    bx = bb & 15; by = (bb >> 4) & 15; bz = bb >> 8;
  }
  size_t zo = (size_t)bz * R * S;
  in += zo; outp += zo;
  int r0 = by * 128, s0 = bx * 32;
  #pragma unroll
  for (int i = 0; i < 16; i++) {
    int lin = i*256 + tid;
    int rr = lin >> 5, ss = lin & 31;
    tileS[rr][ss] = in[(size_t)(r0 + rr) * S + s0 + ss];
  }
  __syncthreads();
  #pragma unroll
  for (int i = 0; i < 4; i++) {
    int lin = i*256 + tid;
    int ss = lin >> 5, rq = lin & 31;
    ushort4 v;
    v.x = (unsigned short)f2bf(tileS[rq*4+0][ss]);
    v.y = (unsigned short)f2bf(tileS[rq*4+1][ss]);
    v.z = (unsigned short)f2bf(tileS[rq*4+2][ss]);
    v.w = (unsigned short)f2bf(tileS[rq*4+3][ss]);
    *(ushort4*)(outp + (size_t)(s0 + ss) * R + r0 + rq*4) = v;
  }
}

// ---------------- prefix+scatter fused: 128 blocks x 64 threads ----------------
// Each block self-computes its chunk's per-expert slot bases by scanning the
// L2-hot counts[] (RBC x 8); block 0 also writes offs/t1s for the GEMMs.
__global__ __launch_bounds__(64) void k_prefscatter(
    const int* __restrict__ counts, const int4* __restrict__ info,
    int* __restrict__ tokl, int2* __restrict__ slots2,
    int* __restrict__ offs, int* __restrict__ t1s)
{
  __shared__ int full_s[8][8];
  __shared__ int part_s[8][8];
  __shared__ int tot_s[8];
  __shared__ int off_s[9];
  __shared__ int cur[8];
  int c = blockIdx.x, t = threadIdx.x;
  int e = t & 7, g = t >> 3;          // 8 experts x 8 groups of 256 router-blocks
  int lim = c * 16;                   // chunk c covers router blocks [0, c*16)
  int full = 0, part = 0;
  for (int i = 0; i < 256; i++) {
    int rb = g*256 + i;
    int v = counts[rb*8 + e];
    full += v;
    if (rb < lim) part += v;
  }
  full_s[e][g] = full; part_s[e][g] = part;
  __syncthreads();
  if (t < 8) {
    int s = 0;
    #pragma unroll
    for (int gg = 0; gg < 8; gg++) s += full_s[t][gg];
    tot_s[t] = s;
  }
  __syncthreads();
  if (t == 0) {
    int o = 0;
    off_s[0] = 0;
    for (int ee = 0; ee < 8; ee++) { o += tot_s[ee]; off_s[ee+1] = o; }
    if (c == 0) {
      offs[0] = 0; t1s[0] = 0;
      int tt = 0;
      for (int ee = 0; ee < 8; ee++) {
        offs[ee+1] = off_s[ee+1];
        tt += (tot_s[ee] + 127) >> 7;
        t1s[ee+1] = tt;
      }
    }
  }
  __syncthreads();
  if (t < 8) {
    int mg = c >> 4;                  // lim/256
    int bse = off_s[t];
    #pragma unroll
    for (int gg = 0; gg < 8; gg++) if (gg < mg) bse += full_s[t][gg];
    bse += part_s[t][mg];
    cur[t] = bse;
  }
  __syncthreads();
  int tok = c*64 + t;
  int4 nfo = info[tok];
  int r0 = atomicAdd(&cur[nfo.x], 1);
  int r1 = atomicAdd(&cur[nfo.y], 1);
  tokl[r0] = tok;
  tokl[r1] = tok;
  slots2[tok] = make_int2(r0, r1);
}

// ---------------- grouped GEMM layer 1: Hs = relu(Xrows @ W1 + b1) ----------------
// 128x128 tile, BK=32, 32KB dbuf + vmcnt(4) pipeline, pair-interleaved XOR LDS.
__global__ __launch_bounds__(256) void k_gemm1(
    const unsigned short* __restrict__ Xbf, const int* __restrict__ tokl,
    const unsigned short* __restrict__ W1b,
    const float* __restrict__ b1, unsigned short* __restrict__ Hs,
    const int* __restrict__ offs, const int* __restrict__ t1s)
{
  __shared__ __align__(16) unsigned short AB[2*8192];   // 32 KB
  int b = blockIdx.x;
  int mo = b >> 7, rr = b & 127;
  int n0 = (rr >> 3) * 128;
  int mt = mo*8 + (rr & 7);
  if (mt >= t1s[8]) return;
  int e = 0;
  #pragma unroll
  for (int i = 0; i < 7; i++) if (mt >= t1s[e+1]) e++;
  int row0 = offs[e] + (mt - t1s[e]) * 128;
  int rowEnd = offs[e+1];
  int tid = threadIdx.x, lane = tid & 63, w = tid >> 6;
  int wm = (w & 1) * 64, wn = (w >> 1) * 64;
  int quad = lane >> 4, l16 = lane & 15;
  const f32x4 zero = {0.f, 0.f, 0.f, 0.f};
  f32x4 acc[4][4];
  #pragma unroll
  for (int i = 0; i < 4; i++)
    #pragma unroll
    for (int j = 0; j < 4; j++) acc[i][j] = zero;
  const unsigned short* Bsrc = W1b + ((size_t)e * H_ + n0) * C_;

  const unsigned short* ga[2]; const unsigned short* gb[2];
  int lao[2], lbo[2];
  #pragma unroll
  for (int j = 0; j < 2; j++) {
    int L = (w*2 + j)*64 + lane;
    int brow, q; stage_decode(L, brow, q);
    int gr = row0 + brow; gr = gr < NASN-1 ? gr : NASN-1;
    int trow = tokl[gr];
    ga[j] = Xbf + (size_t)trow * C_ + q*8;
    gb[j] = Bsrc + (size_t)brow * C_ + q*8;
    lao[j] = (w*2 + j)*512;
    lbo[j] = 4096 + (w*2 + j)*512;
  }
  int rbase = (l16>>1)*64 + ((((l16&1)<<2) + quad) ^ (l16>>1))*8;
  const int KI = C_ / 32;   // 16

  #pragma unroll
  for (int j = 0; j < 2; j++) { g2l16(ga[j], AB + lao[j]); g2l16(gb[j], AB + lbo[j]); }

  for (int ki = 0; ki < KI; ki++) {
    int p = ki & 1;
    if (ki + 1 < KI) {
      int off = (ki + 1) * 32;
      unsigned short* nb = AB + (p ^ 1) * 8192;
      #pragma unroll
      for (int j = 0; j < 2; j++) {
        g2l16(ga[j] + off, nb + lao[j]);
        g2l16(gb[j] + off, nb + lbo[j]);
      }
      asm volatile("s_waitcnt vmcnt(4)" ::: "memory");
    } else {
      asm volatile("s_waitcnt vmcnt(0)" ::: "memory");
    }
    asm volatile("s_barrier" ::: "memory");

    const unsigned short* Ap = AB + p*8192;
    const unsigned short* Bp = Ap + 4096;
    bf16x8 af[4], bfr[4];
    #pragma unroll
    for (int i = 0; i < 4; i++)
      af[i] = *(const bf16x8*)&Ap[wm*32 + i*512 + rbase];
    #pragma unroll
    for (int j = 0; j < 4; j++)
      bfr[j] = *(const bf16x8*)&Bp[wn*32 + j*512 + rbase];
    #pragma unroll
    for (int i = 0; i < 4; i++)
      #pragma unroll
      for (int j = 0; j < 4; j++)
        acc[i][j] = __builtin_amdgcn_mfma_f32_16x16x32_bf16(af[i], bfr[j], acc[i][j], 0, 0, 0);

    asm volatile("s_waitcnt lgkmcnt(0)" ::: "memory");
    asm volatile("s_barrier" ::: "memory");
  }

  // epilogue: per-wave LDS transpose -> coalesced 16B stores
  unsigned short* Lt = AB + w*4096;
  #pragma unroll
  for (int j = 0; j < 4; j++) {
    int n = n0 + wn + j*16 + l16;
    float bias = b1[e * H_ + n];
    #pragma unroll
    for (int i = 0; i < 4; i++)
      #pragma unroll
      for (int r = 0; r < 4; r++) {
        float v = acc[i][j][r] + bias;
        Lt[(i*16 + quad*4 + r)*64 + j*16 + l16] = (unsigned short)f2bf(v > 0.f ? v : 0.f);
      }
  }
  #pragma unroll
  for (int it = 0; it < 8; it++) {
    int rloc = it*8 + (lane >> 3);
    int m = row0 + wm + rloc;
    uint4 vv = *(uint4*)&Lt[rloc*64 + (lane & 7)*8];
    if (m < rowEnd)
      *(uint4*)(Hs + (size_t)m * H_ + n0 + wn + (lane & 7)*8) = vv;
  }
}

// ---------------- grouped GEMM layer 2: Ys(bf16) = Hs @ W2 + b2 ----------------
// 128x128 tile (R6) + pair-interleaved swizzle (R7): 16 MFMA/wave-iter AND
// conflict-free LDS. BK=32, 32KB dbuf, vmcnt(4) pipeline, 1D XCD-swizzled grid.
__global__ __launch_bounds__(256) void k_gemm2(
    const unsigned short* __restrict__ Hs, const unsigned short* __restrict__ W2b,
    const float* __restrict__ b2, unsigned short* __restrict__ Ys,
    const int* __restrict__ offs, const int* __restrict__ t1s)
{
  __shared__ __align__(16) unsigned short AB[2*8192];   // 32 KB
  int b = blockIdx.x;
  int mo = b >> 5, rr = b & 31;
  int n0 = (rr >> 3) * 128;
  int mt = mo*8 + (rr & 7);
  if (mt >= t1s[8]) return;
  int e = 0;
  #pragma unroll
  for (int i = 0; i < 7; i++) if (mt >= t1s[e+1]) e++;
  int row0 = offs[e] + (mt - t1s[e]) * 128;
  int rowEnd = offs[e+1];
  int tid = threadIdx.x, lane = tid & 63, w = tid >> 6;
  int wm = (w & 1) * 64, wn = (w >> 1) * 64;
  int quad = lane >> 4, l16 = lane & 15;
  const f32x4 zero = {0.f, 0.f, 0.f, 0.f};
  f32x4 acc[4][4];
  #pragma unroll
  for (int i = 0; i < 4; i++)
    #pragma unroll
    for (int j = 0; j < 4; j++) acc[i][j] = zero;
  const unsigned short* Bsrc = W2b + ((size_t)e * C_ + n0) * H_;

  const unsigned short* ga[2]; const unsigned short* gb[2];
  int lao[2], lbo[2];
  #pragma unroll
  for (int j = 0; j < 2; j++) {
    int L = (w*2 + j)*64 + lane;
    int brow, q; stage_decode(L, brow, q);
    int gr = row0 + brow; gr = gr < NASN-1 ? gr : NASN-1;
    ga[j] = Hs + (size_t)gr * H_ + q*8;
    gb[j] = Bsrc + (size_t)brow * H_ + q*8;
    lao[j] = (w*2 + j)*512;
    lbo[j] = 4096 + (w*2 + j)*512;
  }
  int rbase = (l16>>1)*64 + ((((l16&1)<<2) + quad) ^ (l16>>1))*8;
  const int KI = H_ / 32;   // 64

  #pragma unroll
  for (int j = 0; j < 2; j++) { g2l16(ga[j], AB + lao[j]); g2l16(gb[j], AB + lbo[j]); }

  for (int ki = 0; ki < KI; ki++) {
    int p = ki & 1;
    if (ki + 1 < KI) {
      int off = (ki + 1) * 32;
      unsigned short* nb = AB + (p ^ 1) * 8192;
      #pragma unroll
      for (int j = 0; j < 2; j++) {
        g2l16(ga[j] + off, nb + lao[j]);
        g2l16(gb[j] + off, nb + lbo[j]);
      }
      asm volatile("s_waitcnt vmcnt(4)" ::: "memory");
    } else {
      asm volatile("s_waitcnt vmcnt(0)" ::: "memory");
    }
    asm volatile("s_barrier" ::: "memory");

    const unsigned short* Ap = AB + p*8192;
    const unsigned short* Bp = Ap + 4096;
    bf16x8 af[4], bfr[4];
    #pragma unroll
    for (int i = 0; i < 4; i++)
      af[i] = *(const bf16x8*)&Ap[wm*32 + i*512 + rbase];
    #pragma unroll
    for (int j = 0; j < 4; j++)
      bfr[j] = *(const bf16x8*)&Bp[wn*32 + j*512 + rbase];
    #pragma unroll
    for (int i = 0; i < 4; i++)
      #pragma unroll
      for (int j = 0; j < 4; j++)
        acc[i][j] = __builtin_amdgcn_mfma_f32_16x16x32_bf16(af[i], bfr[j], acc[i][j], 0, 0, 0);

    asm volatile("s_waitcnt lgkmcnt(0)" ::: "memory");
    asm volatile("s_barrier" ::: "memory");
  }

  // epilogue: per-wave LDS transpose -> coalesced bf16 16B stores
  unsigned short* Lt = AB + w*4096;
  #pragma unroll
  for (int j = 0; j < 4; j++) {
    int n = n0 + wn + j*16 + l16;
    float bias = b2[e * C_ + n];
    #pragma unroll
    for (int i = 0; i < 4; i++)
      #pragma unroll
      for (int r = 0; r < 4; r++)
        Lt[(i*16 + quad*4 + r)*64 + j*16 + l16] =
            (unsigned short)f2bf(acc[i][j][r] + bias);
  }
  #pragma unroll
  for (int it = 0; it < 8; it++) {
    int rloc = it*8 + (lane >> 3);
    int m = row0 + wm + rloc;
    uint4 vv = *(uint4*)&Lt[rloc*64 + (lane & 7)*8];
    if (m < rowEnd)
      *(uint4*)(Ys + (size_t)m * C_ + n0 + wn + (lane & 7)*8) = vv;
  }
}

// ---------------- combine: out[t] = g0*Ys[s0] + g1*Ys[s1] (bf16 Ys) ----------------
__global__ __launch_bounds__(256) void k_combine(
    const unsigned short* __restrict__ Ys, const int4* __restrict__ info,
    const int2* __restrict__ slots2, float* __restrict__ outp)
{
  int t = blockIdx.x * 4 + (threadIdx.x >> 6);
  int lane = threadIdx.x & 63;
  int4 nfo = info[t];
  int2 ss = slots2[t];
  float g0 = __int_as_float(nfo.z), g1 = __int_as_float(nfo.w);
  uint4 a = *(const uint4*)(Ys + (size_t)ss.x * C_ + lane*8);
  uint4 bb = *(const uint4*)(Ys + (size_t)ss.y * C_ + lane*8);
  unsigned int au[4] = {a.x, a.y, a.z, a.w};
  unsigned int bu[4] = {bb.x, bb.y, bb.z, bb.w};
  float vals[8];
  #pragma unroll
  for (int q = 0; q < 4; q++) {
    vals[q*2]   = g0*bf2f(au[q])       + g1*bf2f(bu[q]);
    vals[q*2+1] = g0*bf2f(au[q] >> 16) + g1*bf2f(bu[q] >> 16);
  }
  float4 o0, o1;
  o0.x = vals[0]; o0.y = vals[1]; o0.z = vals[2]; o0.w = vals[3];
  o1.x = vals[4]; o1.y = vals[5]; o1.z = vals[6]; o1.w = vals[7];
  float4* o = (float4*)(outp + (size_t)t * C_ + lane*8);
  o[0] = o0;
  o[1] = o1;
}

extern "C" void kernel_launch(void* const* d_in, const int* in_sizes, int n_in,
                              void* d_out, int out_size, void* d_ws, size_t ws_size,
                              hipStream_t stream)
{
  const float* x  = (const float*)d_in[0];
  const float* Wr = (const float*)d_in[1];
  const float* br = (const float*)d_in[2];
  const float* W1 = (const float*)d_in[3];
  const float* b1 = (const float*)d_in[4];
  const float* W2 = (const float*)d_in[5];
  const float* b2 = (const float*)d_in[6];
  float* out = (float*)d_out;   // [logits 65536 | idx 16384 | out 4194304]
  char* ws = (char*)d_ws;

  int*  counts = (int*)(ws + WS_COUNTS);
  int*  offs   = (int*)(ws + WS_OFFS);
  int*  t1s    = (int*)(ws + WS_T1S);
  int4* info   = (int4*)(ws + WS_INFO);
  int*  tokl   = (int*)(ws + WS_TOKL);
  int2* slots2 = (int2*)(ws + WS_SLOTS);
  unsigned short* Xbf = (unsigned short*)(ws + WS_XBF);
  unsigned short* W1b = (unsigned short*)(ws + WS_W1B);
  unsigned short* W2b = (unsigned short*)(ws + WS_W2B);
  unsigned short* Hs  = (unsigned short*)(ws + WS_HS);
  unsigned short* Ys  = (unsigned short*)(ws + WS_YS);  // aliases Xbf+W1b

  // 5 launches total (was 9): router+transposes fused, prefix+scatter fused,
  // counts written non-atomically (no memset needed).
  k_fused<<<3*RBC, 256, 0, stream>>>(x, Wr, br, out, out + 65536, info,
                                     counts, Xbf, W1, W1b, W2, W2b);
  k_prefscatter<<<128, 64, 0, stream>>>(counts, info, tokl, slots2, offs, t1s);
  k_gemm1<<<17*128, 256, 0, stream>>>(Xbf, tokl, W1b, b1, Hs, offs, t1s);
  k_gemm2<<<17*32, 256, 0, stream>>>(Hs, W2b, b2, Ys, offs, t1s);
  k_combine<<<NTOK/4, 256, 0, stream>>>(Ys, info, slots2, out + 81920);
}